// Round 1
// baseline (856.239 us; speedup 1.0000x reference)
//
#include <hip/hip_runtime.h>

// Problem constants (fixed by setup_inputs)
#define BATCH 8192
#define FEAT  4096
#define MID   512
#define EMB   256
#define KCODE 512

// GEMM tiling
#define BM 64
#define BN 64
#define BK 32

// ---------------------------------------------------------------------------
// Generic fp32 tiled GEMM: C[M,N] = act(A[M,K] @ B[K,N] + bias[N])
// A, B, C row-major. M%64==0, N%64==0, K%32==0 (all shapes here satisfy).
// ---------------------------------------------------------------------------
__global__ __launch_bounds__(256)
void gemm_f32(const float* __restrict__ A, const float* __restrict__ B,
              const float* __restrict__ bias, float* __restrict__ C,
              int M, int N, int K, int doRelu)
{
    __shared__ __align__(16) float As[BK][BM + 4]; // +4 pad: bank-conflict break, keeps 16B align
    __shared__ __align__(16) float Bs[BK][BN];

    const int tid  = threadIdx.x;
    const int row0 = blockIdx.y * BM;
    const int col0 = blockIdx.x * BN;
    const int ty = tid >> 4;   // 0..15
    const int tx = tid & 15;   // 0..15

    float acc[4][4] = {};

    for (int kt = 0; kt < K; kt += BK) {
        // --- stage A tile (BM x BK), float4 global loads, scatter to As[k][m]
        #pragma unroll
        for (int it = 0; it < 2; ++it) {
            int idx = tid + it * 256;          // 0..511
            int r  = idx >> 3;                 // 0..63
            int kq = idx & 7;                  // 0..7 (float4 groups of BK=32)
            float4 av = *(const float4*)(A + (size_t)(row0 + r) * K + kt + kq * 4);
            As[kq * 4 + 0][r] = av.x;
            As[kq * 4 + 1][r] = av.y;
            As[kq * 4 + 2][r] = av.z;
            As[kq * 4 + 3][r] = av.w;
        }
        // --- stage B tile (BK x BN), float4 direct
        #pragma unroll
        for (int it = 0; it < 2; ++it) {
            int idx = tid + it * 256;          // 0..511
            int kr = idx >> 4;                 // 0..31
            int cq = idx & 15;                 // 0..15
            *(float4*)(&Bs[kr][cq * 4]) =
                *(const float4*)(B + (size_t)(kt + kr) * N + col0 + cq * 4);
        }
        __syncthreads();

        #pragma unroll
        for (int k = 0; k < BK; ++k) {
            float4 a = *(const float4*)(&As[k][ty * 4]);
            float4 b = *(const float4*)(&Bs[k][tx * 4]);
            float av[4] = {a.x, a.y, a.z, a.w};
            float bv[4] = {b.x, b.y, b.z, b.w};
            #pragma unroll
            for (int i = 0; i < 4; ++i)
                #pragma unroll
                for (int j = 0; j < 4; ++j)
                    acc[i][j] += av[i] * bv[j];
        }
        __syncthreads();
    }

    #pragma unroll
    for (int i = 0; i < 4; ++i) {
        int r = row0 + ty * 4 + i;
        #pragma unroll
        for (int j = 0; j < 4; ++j) {
            int c = col0 + tx * 4 + j;
            float v = acc[i][j];
            if (bias)   v += bias[c];
            if (doRelu) v = fmaxf(v, 0.0f);
            C[(size_t)r * N + c] = v;
        }
    }
}

// ---------------------------------------------------------------------------
// Normalize codebook rows and write TRANSPOSED: bnT[E][K] = emb[k][e]/(||emb[k]||+1e-12)
// One wave per codebook row.
// ---------------------------------------------------------------------------
__global__ __launch_bounds__(256)
void norm_codes(const float* __restrict__ emb, float* __restrict__ bnT)
{
    int wave = threadIdx.x >> 6;
    int lane = threadIdx.x & 63;
    int c = blockIdx.x * 4 + wave;
    if (c >= KCODE) return;
    const float* er = emb + (size_t)c * EMB;
    float ss = 0.0f;
    #pragma unroll
    for (int k = lane; k < EMB; k += 64) { float v = er[k]; ss += v * v; }
    #pragma unroll
    for (int off = 32; off > 0; off >>= 1) ss += __shfl_down(ss, off, 64);
    ss = __shfl(ss, 0, 64);
    float inv = 1.0f / (sqrtf(ss) + 1e-12f);
    #pragma unroll
    for (int k = lane; k < EMB; k += 64) bnT[(size_t)k * KCODE + c] = er[k] * inv;
}

// ---------------------------------------------------------------------------
// Per-row argmax over sim S[B,K]; writes one-hot row, gathers vq_feat = emb[best],
// stores best index. One wave per batch row; first-index tie-break (numpy argmax).
// ---------------------------------------------------------------------------
__global__ __launch_bounds__(256)
void argmax_vq(const float* __restrict__ S, const float* __restrict__ emb,
               float* __restrict__ onehot, float* __restrict__ vqfeat,
               int* __restrict__ idxOut)
{
    int wave = threadIdx.x >> 6;
    int lane = threadIdx.x & 63;
    int row = blockIdx.x * 4 + wave;
    if (row >= BATCH) return;

    const float* s = S + (size_t)row * KCODE;
    float bestV = -3.402823466e+38f;
    int   bestI = 0;
    #pragma unroll
    for (int c = lane; c < KCODE; c += 64) {
        float v = s[c];
        if (v > bestV) { bestV = v; bestI = c; }   // ascending c => keeps first max
    }
    #pragma unroll
    for (int off = 32; off > 0; off >>= 1) {
        float ov = __shfl_down(bestV, off, 64);
        int   oi = __shfl_down(bestI, off, 64);
        if (ov > bestV || (ov == bestV && oi < bestI)) { bestV = ov; bestI = oi; }
    }
    bestI = __shfl(bestI, 0, 64);
    if (lane == 0) idxOut[row] = bestI;

    float* oh = onehot + (size_t)row * KCODE;
    #pragma unroll
    for (int c = lane; c < KCODE; c += 64) oh[c] = (c == bestI) ? 1.0f : 0.0f;

    const float* er = emb + (size_t)bestI * EMB;
    float* vr = vqfeat + (size_t)row * EMB;
    #pragma unroll
    for (int c = lane; c < EMB; c += 64) vr[c] = er[c];
}

// ---------------------------------------------------------------------------
// decoded[row][:] = Dcode[idx[row]][:]   (float4 copy, 8192 blocks)
// ---------------------------------------------------------------------------
__global__ __launch_bounds__(256)
void gather_decoded(const float* __restrict__ Dcode, const int* __restrict__ idx,
                    float* __restrict__ out)
{
    int row = blockIdx.x;
    int k = idx[row];
    const float4* src = (const float4*)(Dcode + (size_t)k * FEAT);
    float4* dst = (float4*)(out + (size_t)row * FEAT);
    #pragma unroll
    for (int i = threadIdx.x; i < FEAT / 4; i += 256) dst[i] = src[i];
}

// ---------------------------------------------------------------------------
// emb passthrough copy (float4)
// ---------------------------------------------------------------------------
__global__ __launch_bounds__(256)
void copy_f4(const float* __restrict__ src, float* __restrict__ dst, int n4)
{
    int i = blockIdx.x * 256 + threadIdx.x;
    if (i < n4) ((float4*)dst)[i] = ((const float4*)src)[i];
}

// ---------------------------------------------------------------------------
extern "C" void kernel_launch(void* const* d_in, const int* in_sizes, int n_in,
                              void* d_out, int out_size, void* d_ws, size_t ws_size,
                              hipStream_t stream)
{
    const float* x      = (const float*)d_in[0];  // [B, FEAT]
    const float* enc_w1 = (const float*)d_in[1];  // [FEAT, MID]
    const float* enc_b1 = (const float*)d_in[2];  // [MID]
    const float* enc_w2 = (const float*)d_in[3];  // [MID, EMB]
    const float* enc_b2 = (const float*)d_in[4];  // [EMB]
    const float* emb    = (const float*)d_in[5];  // [K, EMB]
    const float* dec_w1 = (const float*)d_in[6];  // [EMB, MID]
    const float* dec_b1 = (const float*)d_in[7];  // [MID]
    const float* dec_w2 = (const float*)d_in[8];  // [MID, FEAT]
    const float* dec_b2 = (const float*)d_in[9];  // [FEAT]

    float* out = (float*)d_out;
    // output layout (flat, return order)
    float* out_encoded = out;                                   // [B, EMB]
    float* out_vqfeat  = out + (size_t)BATCH * EMB;             // [B, EMB]
    float* out_onehot  = out + (size_t)2 * BATCH * EMB;         // [B, K]
    float* out_decoded = out + (size_t)2 * BATCH * EMB + (size_t)BATCH * KCODE; // [B, FEAT]
    float* out_emb     = out_decoded + (size_t)BATCH * FEAT;    // [K, EMB]

    // workspace layout (floats)
    float* ws   = (float*)d_ws;
    float* h    = ws;                                  // [B, MID]      4,194,304
    float* S    = h   + (size_t)BATCH * MID;           // [B, K]        4,194,304
    float* bnT  = S   + (size_t)BATCH * KCODE;         // [EMB, K]        131,072
    float* tmid = bnT + (size_t)EMB * KCODE;           // [K, MID]        262,144
    float* Dc   = tmid + (size_t)KCODE * MID;          // [K, FEAT]     2,097,152
    int*   idx  = (int*)(Dc + (size_t)KCODE * FEAT);   // [B]

    // 1. codebook normalization (transposed) — fp32, argmax-critical
    norm_codes<<<dim3(KCODE / 4), dim3(256), 0, stream>>>(emb, bnT);

    // 2. emb passthrough
    copy_f4<<<dim3((KCODE * EMB / 4 + 255) / 256), dim3(256), 0, stream>>>(
        emb, out_emb, KCODE * EMB / 4);

    // 3. h = relu(x @ enc_w1 + b1)   [B, MID]  — the 34.4 GF fp32 GEMM
    gemm_f32<<<dim3(MID / BN, BATCH / BM), dim3(256), 0, stream>>>(
        x, enc_w1, enc_b1, h, BATCH, MID, FEAT, 1);

    // 4. encoded = h @ enc_w2 + b2   [B, EMB]  (no relu) -> directly to out
    gemm_f32<<<dim3(EMB / BN, BATCH / BM), dim3(256), 0, stream>>>(
        h, enc_w2, enc_b2, out_encoded, BATCH, EMB, MID, 0);

    // 5. S = encoded @ bnT           [B, K]    (feature normalization skipped:
    //    positive per-row scaling is argmax-invariant)
    gemm_f32<<<dim3(KCODE / BN, BATCH / BM), dim3(256), 0, stream>>>(
        out_encoded, bnT, nullptr, S, BATCH, KCODE, EMB, 0);

    // 6. argmax -> one-hot, vq_feat, idx
    argmax_vq<<<dim3(BATCH / 4), dim3(256), 0, stream>>>(
        S, emb, out_onehot, out_vqfeat, idx);

    // 7. decoder on the CODEBOOK only (512 distinct vq rows):
    //    tmid = relu(emb @ dec_w1 + b1)   [K, MID]
    gemm_f32<<<dim3(MID / BN, KCODE / BM), dim3(256), 0, stream>>>(
        emb, dec_w1, dec_b1, tmid, KCODE, MID, EMB, 1);

    //    Dcode = relu(tmid @ dec_w2 + b2) [K, FEAT]
    gemm_f32<<<dim3(FEAT / BN, KCODE / BM), dim3(256), 0, stream>>>(
        tmid, dec_w2, dec_b2, Dc, KCODE, FEAT, MID, 1);

    // 8. decoded[i] = Dcode[idx[i]]
    gather_decoded<<<dim3(BATCH), dim3(256), 0, stream>>>(Dc, idx, out_decoded);
}

// Round 2
// 742.407 us; speedup vs baseline: 1.1533x; 1.1533x over previous
//
#include <hip/hip_runtime.h>

// Problem constants (fixed by setup_inputs)
#define BATCH 8192
#define FEAT  4096
#define MID   512
#define EMB   256
#define KCODE 512

typedef _Float16 half8 __attribute__((ext_vector_type(8)));
typedef float floatx4 __attribute__((ext_vector_type(4)));

// Scales (powers of 2; descaled exactly in epilogues)
#define SC_X    512.0f
#define SC_W    4096.0f
#define SC_H    512.0f
#define SC_ENC  4096.0f
#define SC_CODE 4096.0f
#define DS_G1   (1.0f / (512.0f * 4096.0f))   // 2^-21
#define DS_G2   (1.0f / (512.0f * 4096.0f))   // 2^-21
#define DS_G3   (1.0f / (4096.0f * 4096.0f))  // 2^-24

#define GLD16(gp, lp)                                                          \
    __builtin_amdgcn_global_load_lds(                                          \
        (const __attribute__((address_space(1))) void*)(gp),                   \
        (__attribute__((address_space(3))) void*)(lp), 16, 0, 0)

// ---------------------------------------------------------------------------
// f16x3 MFMA GEMM: C[M,N] = act( (A_hi+A_lo)[M,K] @ (B_hi+B_lo)^T + bias )
// A given as hi/lo f16 [M][K]; B given TRANSPOSED hi/lo f16 [N][K].
// acc_fp32 accumulates hi*hi + hi*lo + lo*hi (lo*lo ~2^-24, dropped).
// Epilogue: v = acc*descale + bias, optional relu; writes fp32 and/or
// re-split scaled f16 hi/lo.
// Tile 128x128, BK=32, 256 threads (2x2 waves of 64x64), global_load_lds.
// ---------------------------------------------------------------------------
__global__ __launch_bounds__(256)
void gemm_f16x3(const _Float16* __restrict__ Ahg, const _Float16* __restrict__ Alg,
                const _Float16* __restrict__ BTh, const _Float16* __restrict__ BTl,
                const float* __restrict__ bias, float descale, int relu,
                float* __restrict__ outF,
                _Float16* __restrict__ outHi, _Float16* __restrict__ outLo,
                float outScale, int M, int N, int K)
{
    __shared__ _Float16 Ah[128 * 32];
    __shared__ _Float16 Al[128 * 32];
    __shared__ _Float16 Bh[128 * 32];
    __shared__ _Float16 Bl[128 * 32];

    const int tid  = threadIdx.x;
    const int lane = tid & 63;
    const int wave = tid >> 6;
    const int wm = wave >> 1, wn = wave & 1;
    const int l15  = lane & 15;
    const int quad = lane >> 4;
    const int q8   = quad * 8;
    const int row0 = blockIdx.y * 128;
    const int col0 = blockIdx.x * 128;

    // staging: thread tid covers 8 f16 at tile-linear o = it*2048 + tid*8
    const int sr = tid >> 2;          // 0..63
    const int sc = (tid & 3) * 8;     // 0,8,16,24
    const size_t aB0 = (size_t)(row0 + sr) * K + sc;
    const size_t aB1 = (size_t)(row0 + 64 + sr) * K + sc;
    const size_t bB0 = (size_t)(col0 + sr) * K + sc;
    const size_t bB1 = (size_t)(col0 + 64 + sr) * K + sc;
    const int l0 = tid * 8, l1 = 2048 + tid * 8;

    floatx4 acc[4][4] = {};

    for (int kt = 0; kt < K; kt += 32) {
        GLD16(Ahg + aB0 + kt, &Ah[l0]);
        GLD16(Ahg + aB1 + kt, &Ah[l1]);
        GLD16(Alg + aB0 + kt, &Al[l0]);
        GLD16(Alg + aB1 + kt, &Al[l1]);
        GLD16(BTh + bB0 + kt, &Bh[l0]);
        GLD16(BTh + bB1 + kt, &Bh[l1]);
        GLD16(BTl + bB0 + kt, &Bl[l0]);
        GLD16(BTl + bB1 + kt, &Bl[l1]);
        __syncthreads();

        half8 ah[4], al4[4], bh[4], bl4[4];
        #pragma unroll
        for (int i = 0; i < 4; ++i) {
            int ra = (wm * 64 + i * 16 + l15) * 32 + q8;
            ah[i]  = *(const half8*)&Ah[ra];
            al4[i] = *(const half8*)&Al[ra];
            int rb = (wn * 64 + i * 16 + l15) * 32 + q8;
            bh[i]  = *(const half8*)&Bh[rb];
            bl4[i] = *(const half8*)&Bl[rb];
        }
        #pragma unroll
        for (int i = 0; i < 4; ++i)
            #pragma unroll
            for (int j = 0; j < 4; ++j) {
                acc[i][j] = __builtin_amdgcn_mfma_f32_16x16x32_f16(ah[i],  bh[j],  acc[i][j], 0, 0, 0);
                acc[i][j] = __builtin_amdgcn_mfma_f32_16x16x32_f16(ah[i],  bl4[j], acc[i][j], 0, 0, 0);
                acc[i][j] = __builtin_amdgcn_mfma_f32_16x16x32_f16(al4[i], bh[j],  acc[i][j], 0, 0, 0);
            }
        __syncthreads();
    }

    // Epilogue. C/D layout (verified m89): col = lane&15, row = quad*4 + reg.
    #pragma unroll
    for (int j = 0; j < 4; ++j) {
        int col = col0 + wn * 64 + j * 16 + l15;
        float bcol = bias ? bias[col] : 0.0f;
        #pragma unroll
        for (int i = 0; i < 4; ++i) {
            #pragma unroll
            for (int t = 0; t < 4; ++t) {
                int r = row0 + wm * 64 + i * 16 + quad * 4 + t;
                float v = acc[i][j][t] * descale + bcol;
                if (relu) v = fmaxf(v, 0.0f);
                size_t o = (size_t)r * N + col;
                if (outF) outF[o] = v;
                if (outHi) {
                    float sv = v * outScale;
                    _Float16 h = (_Float16)sv;
                    outHi[o] = h;
                    outLo[o] = (_Float16)(sv - (float)h);
                }
            }
        }
    }
}

// ---------------------------------------------------------------------------
// Elementwise fp32 -> scaled f16 hi/lo split. 8 elements/thread.
// ---------------------------------------------------------------------------
__global__ __launch_bounds__(256)
void split_f16(const float* __restrict__ src, _Float16* __restrict__ hi,
               _Float16* __restrict__ lo, float scale, int n8)
{
    int i = blockIdx.x * 256 + threadIdx.x;
    if (i >= n8) return;
    const float4* s4 = (const float4*)src;
    float4 a = s4[i * 2], b = s4[i * 2 + 1];
    float v[8] = {a.x, a.y, a.z, a.w, b.x, b.y, b.z, b.w};
    half8 hv, lv;
    #pragma unroll
    for (int j = 0; j < 8; ++j) {
        float sv = v[j] * scale;
        _Float16 h = (_Float16)sv;
        hv[j] = h;
        lv[j] = (_Float16)(sv - (float)h);
    }
    ((half8*)hi)[i] = hv;
    ((half8*)lo)[i] = lv;
}

// ---------------------------------------------------------------------------
// Transpose fp32 [R][C] -> scaled f16 hi/lo [C][R]. 32x32 LDS tiles.
// ---------------------------------------------------------------------------
__global__ __launch_bounds__(256)
void transpose_split(const float* __restrict__ src, _Float16* __restrict__ hi,
                     _Float16* __restrict__ lo, float scale, int R, int C)
{
    __shared__ float t[32][33];
    int tx = threadIdx.x & 31, ty = threadIdx.x >> 5;   // ty 0..7
    int r0 = blockIdx.y * 32, c0 = blockIdx.x * 32;
    #pragma unroll
    for (int p = 0; p < 4; ++p) {
        int r = ty + p * 8;
        t[r][tx] = src[(size_t)(r0 + r) * C + c0 + tx];
    }
    __syncthreads();
    #pragma unroll
    for (int p = 0; p < 4; ++p) {
        int oc = ty + p * 8;                 // output row = c0+oc
        float v = t[tx][oc] * scale;
        _Float16 h = (_Float16)v;
        size_t o = (size_t)(c0 + oc) * R + r0 + tx;
        hi[o] = h;
        lo[o] = (_Float16)(v - (float)h);
    }
}

// ---------------------------------------------------------------------------
// Normalize codebook rows (fp32), emit scaled f16 hi/lo [K][E] (mode 0)
// or fp32 transposed bnT [E][K] (mode 1, fallback path).
// ---------------------------------------------------------------------------
__global__ __launch_bounds__(256)
void norm_codes(const float* __restrict__ emb, _Float16* __restrict__ cnHi,
                _Float16* __restrict__ cnLo, float* __restrict__ bnT, int mode)
{
    int wave = threadIdx.x >> 6;
    int lane = threadIdx.x & 63;
    int c = blockIdx.x * 4 + wave;
    if (c >= KCODE) return;
    const float* er = emb + (size_t)c * EMB;
    float ss = 0.0f;
    #pragma unroll
    for (int k = lane; k < EMB; k += 64) { float v = er[k]; ss += v * v; }
    #pragma unroll
    for (int off = 32; off > 0; off >>= 1) ss += __shfl_down(ss, off, 64);
    ss = __shfl(ss, 0, 64);
    float inv = 1.0f / (sqrtf(ss) + 1e-12f);
    if (mode == 0) {
        #pragma unroll
        for (int k = lane; k < EMB; k += 64) {
            float v = er[k] * inv * SC_CODE;
            _Float16 h = (_Float16)v;
            cnHi[(size_t)c * EMB + k] = h;
            cnLo[(size_t)c * EMB + k] = (_Float16)(v - (float)h);
        }
    } else {
        #pragma unroll
        for (int k = lane; k < EMB; k += 64) bnT[(size_t)k * KCODE + c] = er[k] * inv;
    }
}

// ---------------------------------------------------------------------------
// fp32 tiled GEMM (decoder + fallback path). C = act(A@B + bias).
// ---------------------------------------------------------------------------
#define BM 64
#define BN 64
#define BK 32
__global__ __launch_bounds__(256)
void gemm_f32(const float* __restrict__ A, const float* __restrict__ B,
              const float* __restrict__ bias, float* __restrict__ C,
              int M, int N, int K, int doRelu)
{
    __shared__ __align__(16) float As[BK][BM + 4];
    __shared__ __align__(16) float Bs[BK][BN];

    const int tid  = threadIdx.x;
    const int row0 = blockIdx.y * BM;
    const int col0 = blockIdx.x * BN;
    const int ty = tid >> 4;
    const int tx = tid & 15;

    float acc[4][4] = {};

    for (int kt = 0; kt < K; kt += BK) {
        #pragma unroll
        for (int it = 0; it < 2; ++it) {
            int idx = tid + it * 256;
            int r  = idx >> 3;
            int kq = idx & 7;
            float4 av = *(const float4*)(A + (size_t)(row0 + r) * K + kt + kq * 4);
            As[kq * 4 + 0][r] = av.x;
            As[kq * 4 + 1][r] = av.y;
            As[kq * 4 + 2][r] = av.z;
            As[kq * 4 + 3][r] = av.w;
        }
        #pragma unroll
        for (int it = 0; it < 2; ++it) {
            int idx = tid + it * 256;
            int kr = idx >> 4;
            int cq = idx & 15;
            *(float4*)(&Bs[kr][cq * 4]) =
                *(const float4*)(B + (size_t)(kt + kr) * N + col0 + cq * 4);
        }
        __syncthreads();

        #pragma unroll
        for (int k = 0; k < BK; ++k) {
            float4 a = *(const float4*)(&As[k][ty * 4]);
            float4 b = *(const float4*)(&Bs[k][tx * 4]);
            float av[4] = {a.x, a.y, a.z, a.w};
            float bv[4] = {b.x, b.y, b.z, b.w};
            #pragma unroll
            for (int i = 0; i < 4; ++i)
                #pragma unroll
                for (int j = 0; j < 4; ++j)
                    acc[i][j] += av[i] * bv[j];
        }
        __syncthreads();
    }

    #pragma unroll
    for (int i = 0; i < 4; ++i) {
        int r = row0 + ty * 4 + i;
        #pragma unroll
        for (int j = 0; j < 4; ++j) {
            int c = col0 + tx * 4 + j;
            float v = acc[i][j];
            if (bias)   v += bias[c];
            if (doRelu) v = fmaxf(v, 0.0f);
            C[(size_t)r * N + c] = v;
        }
    }
}

// ---------------------------------------------------------------------------
// Per-row argmax over S[B,K] -> one-hot, vq_feat gather, index.
// First-index tie-break (numpy argmax semantics).
// ---------------------------------------------------------------------------
__global__ __launch_bounds__(256)
void argmax_vq(const float* __restrict__ S, const float* __restrict__ emb,
               float* __restrict__ onehot, float* __restrict__ vqfeat,
               int* __restrict__ idxOut)
{
    int wave = threadIdx.x >> 6;
    int lane = threadIdx.x & 63;
    int row = blockIdx.x * 4 + wave;
    if (row >= BATCH) return;

    const float* s = S + (size_t)row * KCODE;
    float bestV = -3.402823466e+38f;
    int   bestI = 0;
    #pragma unroll
    for (int c = lane; c < KCODE; c += 64) {
        float v = s[c];
        if (v > bestV) { bestV = v; bestI = c; }
    }
    #pragma unroll
    for (int off = 32; off > 0; off >>= 1) {
        float ov = __shfl_down(bestV, off, 64);
        int   oi = __shfl_down(bestI, off, 64);
        if (ov > bestV || (ov == bestV && oi < bestI)) { bestV = ov; bestI = oi; }
    }
    bestI = __shfl(bestI, 0, 64);
    if (lane == 0) idxOut[row] = bestI;

    float* oh = onehot + (size_t)row * KCODE;
    #pragma unroll
    for (int c = lane; c < KCODE; c += 64) oh[c] = (c == bestI) ? 1.0f : 0.0f;

    const float* er = emb + (size_t)bestI * EMB;
    float* vr = vqfeat + (size_t)row * EMB;
    #pragma unroll
    for (int c = lane; c < EMB; c += 64) vr[c] = er[c];
}

__global__ __launch_bounds__(256)
void gather_decoded(const float* __restrict__ Dcode, const int* __restrict__ idx,
                    float* __restrict__ out)
{
    int row = blockIdx.x;
    int k = idx[row];
    const float4* src = (const float4*)(Dcode + (size_t)k * FEAT);
    float4* dst = (float4*)(out + (size_t)row * FEAT);
    #pragma unroll
    for (int i = threadIdx.x; i < FEAT / 4; i += 256) dst[i] = src[i];
}

__global__ __launch_bounds__(256)
void copy_f4(const float* __restrict__ src, float* __restrict__ dst, int n4)
{
    int i = blockIdx.x * 256 + threadIdx.x;
    if (i < n4) ((float4*)dst)[i] = ((const float4*)src)[i];
}

// ---------------------------------------------------------------------------
extern "C" void kernel_launch(void* const* d_in, const int* in_sizes, int n_in,
                              void* d_out, int out_size, void* d_ws, size_t ws_size,
                              hipStream_t stream)
{
    const float* x      = (const float*)d_in[0];
    const float* enc_w1 = (const float*)d_in[1];
    const float* enc_b1 = (const float*)d_in[2];
    const float* enc_w2 = (const float*)d_in[3];
    const float* enc_b2 = (const float*)d_in[4];
    const float* emb    = (const float*)d_in[5];
    const float* dec_w1 = (const float*)d_in[6];
    const float* dec_b1 = (const float*)d_in[7];
    const float* dec_w2 = (const float*)d_in[8];
    const float* dec_b2 = (const float*)d_in[9];

    float* out = (float*)d_out;
    float* out_encoded = out;
    float* out_vqfeat  = out + (size_t)BATCH * EMB;
    float* out_onehot  = out + (size_t)2 * BATCH * EMB;
    float* out_decoded = out + (size_t)2 * BATCH * EMB + (size_t)BATCH * KCODE;
    float* out_emb     = out_decoded + (size_t)BATCH * FEAT;

    // ------- workspace layout (f16 path), bytes -------
    char* w = (char*)d_ws;
    _Float16* x_hi   = (_Float16*)w;                    w += (size_t)BATCH * FEAT * 2;
    _Float16* x_lo   = (_Float16*)w;                    w += (size_t)BATCH * FEAT * 2;
    _Float16* w1T_hi = (_Float16*)w;                    w += (size_t)FEAT * MID * 2;
    _Float16* w1T_lo = (_Float16*)w;                    w += (size_t)FEAT * MID * 2;
    _Float16* h_hi   = (_Float16*)w;                    w += (size_t)BATCH * MID * 2;
    _Float16* h_lo   = (_Float16*)w;                    w += (size_t)BATCH * MID * 2;
    _Float16* w2T_hi = (_Float16*)w;                    w += (size_t)MID * EMB * 2;
    _Float16* w2T_lo = (_Float16*)w;                    w += (size_t)MID * EMB * 2;
    _Float16* enc_hi = (_Float16*)w;                    w += (size_t)BATCH * EMB * 2;
    _Float16* enc_lo = (_Float16*)w;                    w += (size_t)BATCH * EMB * 2;
    _Float16* cn_hi  = (_Float16*)w;                    w += (size_t)KCODE * EMB * 2;
    _Float16* cn_lo  = (_Float16*)w;                    w += (size_t)KCODE * EMB * 2;
    float*    S      = (float*)w;                       w += (size_t)BATCH * KCODE * 4;
    float*    tmid   = (float*)w;                       w += (size_t)KCODE * MID * 4;
    float*    Dc     = (float*)w;                       w += (size_t)KCODE * FEAT * 4;
    int*      idx    = (int*)w;                         w += (size_t)BATCH * 4;
    size_t need = (size_t)(w - (char*)d_ws);

    if (ws_size >= need) {
        // =================== f16x3 MFMA path ===================
        // 1. input conversions
        split_f16<<<dim3(BATCH * FEAT / 8 / 256), dim3(256), 0, stream>>>(
            x, x_hi, x_lo, SC_X, BATCH * FEAT / 8);
        transpose_split<<<dim3(MID / 32, FEAT / 32), dim3(256), 0, stream>>>(
            enc_w1, w1T_hi, w1T_lo, SC_W, FEAT, MID);
        transpose_split<<<dim3(EMB / 32, MID / 32), dim3(256), 0, stream>>>(
            enc_w2, w2T_hi, w2T_lo, SC_W, MID, EMB);
        norm_codes<<<dim3(KCODE / 4), dim3(256), 0, stream>>>(
            emb, cn_hi, cn_lo, nullptr, 0);
        copy_f4<<<dim3((KCODE * EMB / 4 + 255) / 256), dim3(256), 0, stream>>>(
            emb, out_emb, KCODE * EMB / 4);

        // 2. h = relu(x @ w1 + b1) -> scaled f16 hi/lo directly
        gemm_f16x3<<<dim3(MID / 128, BATCH / 128), dim3(256), 0, stream>>>(
            x_hi, x_lo, w1T_hi, w1T_lo, enc_b1, DS_G1, 1,
            nullptr, h_hi, h_lo, SC_H, BATCH, MID, FEAT);

        // 3. encoded = h @ w2 + b2 -> fp32 output + scaled hi/lo
        gemm_f16x3<<<dim3(EMB / 128, BATCH / 128), dim3(256), 0, stream>>>(
            h_hi, h_lo, w2T_hi, w2T_lo, enc_b2, DS_G2, 0,
            out_encoded, enc_hi, enc_lo, SC_ENC, BATCH, EMB, MID);

        // 4. S = encoded @ normalized_codes^T (feature norm skipped: argmax-invariant)
        gemm_f16x3<<<dim3(KCODE / 128, BATCH / 128), dim3(256), 0, stream>>>(
            enc_hi, enc_lo, cn_hi, cn_lo, nullptr, DS_G3, 0,
            S, nullptr, nullptr, 1.0f, BATCH, KCODE, EMB);

        // 5. argmax -> one-hot, vq_feat, idx
        argmax_vq<<<dim3(BATCH / 4), dim3(256), 0, stream>>>(
            S, emb, out_onehot, out_vqfeat, idx);

        // 6. decoder on codebook only (512 distinct rows), fp32
        gemm_f32<<<dim3(MID / BN, KCODE / BM), dim3(256), 0, stream>>>(
            emb, dec_w1, dec_b1, tmid, KCODE, MID, EMB, 1);
        gemm_f32<<<dim3(FEAT / BN, KCODE / BM), dim3(256), 0, stream>>>(
            tmid, dec_w2, dec_b2, Dc, KCODE, FEAT, MID, 1);

        // 7. decoded[i] = Dcode[idx[i]]
        gather_decoded<<<dim3(BATCH), dim3(256), 0, stream>>>(Dc, idx, out_decoded);
    } else {
        // =================== fp32 fallback (round-1 path) ===================
        char* f = (char*)d_ws;
        float* h    = (float*)f;                        f += (size_t)BATCH * MID * 4;
        float* Sf   = (float*)f;                        f += (size_t)BATCH * KCODE * 4;
        float* bnT  = (float*)f;                        f += (size_t)EMB * KCODE * 4;
        float* tm   = (float*)f;                        f += (size_t)KCODE * MID * 4;
        float* Dcf  = (float*)f;                        f += (size_t)KCODE * FEAT * 4;
        int*   idf  = (int*)f;

        norm_codes<<<dim3(KCODE / 4), dim3(256), 0, stream>>>(
            emb, nullptr, nullptr, bnT, 1);
        copy_f4<<<dim3((KCODE * EMB / 4 + 255) / 256), dim3(256), 0, stream>>>(
            emb, out_emb, KCODE * EMB / 4);
        gemm_f32<<<dim3(MID / BN, BATCH / BM), dim3(256), 0, stream>>>(
            x, enc_w1, enc_b1, h, BATCH, MID, FEAT, 1);
        gemm_f32<<<dim3(EMB / BN, BATCH / BM), dim3(256), 0, stream>>>(
            h, enc_w2, enc_b2, out_encoded, BATCH, EMB, MID, 0);
        gemm_f32<<<dim3(KCODE / BN, BATCH / BM), dim3(256), 0, stream>>>(
            out_encoded, bnT, nullptr, Sf, BATCH, KCODE, EMB, 0);
        argmax_vq<<<dim3(BATCH / 4), dim3(256), 0, stream>>>(
            Sf, emb, out_onehot, out_vqfeat, idf);
        gemm_f32<<<dim3(MID / BN, KCODE / BM), dim3(256), 0, stream>>>(
            emb, dec_w1, dec_b1, tm, KCODE, MID, EMB, 1);
        gemm_f32<<<dim3(FEAT / BN, KCODE / BM), dim3(256), 0, stream>>>(
            tm, dec_w2, dec_b2, Dcf, KCODE, FEAT, MID, 1);
        gather_decoded<<<dim3(BATCH), dim3(256), 0, stream>>>(Dcf, idf, out_decoded);
    }
}

// Round 3
// 625.864 us; speedup vs baseline: 1.3681x; 1.1862x over previous
//
#include <hip/hip_runtime.h>

#define BATCH 8192
#define FEAT  4096
#define MID   512
#define EMB   256
#define KCODE 512

typedef _Float16 half8 __attribute__((ext_vector_type(8)));
typedef float floatx4 __attribute__((ext_vector_type(4)));

// Power-of-2 scales; descaled exactly in epilogues.
#define SC_X    512.0f
#define SC_W    4096.0f
#define SC_H    512.0f
#define SC_ENC  4096.0f
#define SC_CODE 4096.0f
#define SC_EMB  4096.0f
#define SC_TM   512.0f
#define DS_G1   (1.0f / (SC_X   * SC_W))
#define DS_G2   (1.0f / (SC_H   * SC_W))
#define DS_G3   (1.0f / (SC_ENC * SC_CODE))
#define DS_D1   (1.0f / (SC_EMB * SC_W))
#define DS_D2   (1.0f / (SC_TM  * SC_W))

// ---------------------------------------------------------------------------
// Register-pipelined f16 MFMA GEMM, 128x128 tile, BK=32, 256 threads (2x2
// waves). C = act( A @ B^T * descale + bias ).
//   A: either fp32 [M][K] (split to hi/lo f16 in-register, aScale applied)
//      or pre-split f16 hi/lo [M][K].
//   B: pre-split (pre-scaled) f16 hi/lo, TRANSPOSED [N][K].
//   nTerms==3: hi*hi + hi*lo + lo*hi (fp32-equivalent, ~2^-22 rel error).
//   nTerms==1: hi*hi only (~5e-4 rel error; decoder path).
// Pipeline: loads for tile k+1 go global->VGPR while MFMAs consume LDS tile k;
// no global_load_lds => s_barrier needs no vmcnt(0) drain (the m97 stall).
// swz: remap so the 4 N-blocks sharing an A-stripe are == mod 8 (same XCD),
// giving L2-shared A fetches (requires gridN==4, gridM%8==0, 1-D launch).
// ---------------------------------------------------------------------------
__global__ __launch_bounds__(256)
void gemm_rp(const float* __restrict__ Af32,
             const _Float16* __restrict__ Ahg, const _Float16* __restrict__ Alg,
             const _Float16* __restrict__ BTh, const _Float16* __restrict__ BTl,
             const float* __restrict__ bias, float aScale, float descale, int relu,
             float* __restrict__ outF,
             _Float16* __restrict__ outHi, _Float16* __restrict__ outLo,
             float outScale, int M, int N, int K, int nTerms, int swz)
{
    __shared__ _Float16 Ah[128 * 32];
    __shared__ _Float16 Al[128 * 32];
    __shared__ _Float16 Bh[128 * 32];
    __shared__ _Float16 Bl[128 * 32];

    const int tid  = threadIdx.x;
    const int lane = tid & 63;
    const int wave = tid >> 6;
    const int wm = wave >> 1, wn = wave & 1;
    const int l15  = lane & 15;
    const int quad = lane >> 4;
    const int q8   = quad * 8;

    int bm, bn;
    if (swz) { int b = blockIdx.x; bm = ((b >> 5) << 3) | (b & 7); bn = (b >> 3) & 3; }
    else     { bm = blockIdx.y; bn = blockIdx.x; }
    const int row0 = bm * 128, col0 = bn * 128;

    // staging: thread t covers row = t>>1 (0..127), k-offset (t&1)*16
    const int srow = tid >> 1;
    const int sk   = (tid & 1) * 16;
    const size_t aOff = (size_t)(row0 + srow) * K + sk;
    const size_t bOff = (size_t)(col0 + srow) * K + sk;
    const int lA = srow * 32 + sk;   // LDS half-index

    floatx4 acc[4][4] = {};
    float4 fa[4];
    half8  rah[2], ral[2], rbh[2], rbl[2];

    auto loadTile = [&](int kt) {
        if (Af32) {
            const float* p = Af32 + aOff + kt;
            fa[0] = *(const float4*)(p);
            fa[1] = *(const float4*)(p + 4);
            fa[2] = *(const float4*)(p + 8);
            fa[3] = *(const float4*)(p + 12);
        } else {
            const _Float16* p = Ahg + aOff + kt;
            rah[0] = *(const half8*)(p);
            rah[1] = *(const half8*)(p + 8);
            if (nTerms == 3) {
                const _Float16* q = Alg + aOff + kt;
                ral[0] = *(const half8*)(q);
                ral[1] = *(const half8*)(q + 8);
            }
        }
        const _Float16* pb = BTh + bOff + kt;
        rbh[0] = *(const half8*)(pb);
        rbh[1] = *(const half8*)(pb + 8);
        if (nTerms == 3) {
            const _Float16* qb = BTl + bOff + kt;
            rbl[0] = *(const half8*)(qb);
            rbl[1] = *(const half8*)(qb + 8);
        }
    };

    auto writeTile = [&]() {
        if (Af32) {
            const float* f = (const float*)fa;   // 16 staged floats
            half8 hv0, hv1, lv0, lv1;
            #pragma unroll
            for (int e = 0; e < 8; ++e) {
                float v = f[e] * aScale;
                _Float16 h = (_Float16)v;
                hv0[e] = h; lv0[e] = (_Float16)(v - (float)h);
            }
            #pragma unroll
            for (int e = 0; e < 8; ++e) {
                float v = f[8 + e] * aScale;
                _Float16 h = (_Float16)v;
                hv1[e] = h; lv1[e] = (_Float16)(v - (float)h);
            }
            *(half8*)&Ah[lA] = hv0; *(half8*)&Ah[lA + 8] = hv1;
            if (nTerms == 3) { *(half8*)&Al[lA] = lv0; *(half8*)&Al[lA + 8] = lv1; }
        } else {
            *(half8*)&Ah[lA] = rah[0]; *(half8*)&Ah[lA + 8] = rah[1];
            if (nTerms == 3) { *(half8*)&Al[lA] = ral[0]; *(half8*)&Al[lA + 8] = ral[1]; }
        }
        *(half8*)&Bh[lA] = rbh[0]; *(half8*)&Bh[lA + 8] = rbh[1];
        if (nTerms == 3) { *(half8*)&Bl[lA] = rbl[0]; *(half8*)&Bl[lA + 8] = rbl[1]; }
    };

    auto compute = [&]() {
        half8 xah[4], xal[4], xbh[4], xbl[4];
        #pragma unroll
        for (int i = 0; i < 4; ++i) {
            int ra = (wm * 64 + i * 16 + l15) * 32 + q8;
            int rb = (wn * 64 + i * 16 + l15) * 32 + q8;
            xah[i] = *(const half8*)&Ah[ra];
            xbh[i] = *(const half8*)&Bh[rb];
            if (nTerms == 3) {
                xal[i] = *(const half8*)&Al[ra];
                xbl[i] = *(const half8*)&Bl[rb];
            }
        }
        if (nTerms == 3) {
            #pragma unroll
            for (int i = 0; i < 4; ++i)
                #pragma unroll
                for (int j = 0; j < 4; ++j) {
                    acc[i][j] = __builtin_amdgcn_mfma_f32_16x16x32_f16(xah[i], xbh[j], acc[i][j], 0, 0, 0);
                    acc[i][j] = __builtin_amdgcn_mfma_f32_16x16x32_f16(xah[i], xbl[j], acc[i][j], 0, 0, 0);
                    acc[i][j] = __builtin_amdgcn_mfma_f32_16x16x32_f16(xal[i], xbh[j], acc[i][j], 0, 0, 0);
                }
        } else {
            #pragma unroll
            for (int i = 0; i < 4; ++i)
                #pragma unroll
                for (int j = 0; j < 4; ++j)
                    acc[i][j] = __builtin_amdgcn_mfma_f32_16x16x32_f16(xah[i], xbh[j], acc[i][j], 0, 0, 0);
        }
    };

    loadTile(0);
    writeTile();
    __syncthreads();
    for (int kt = 32; kt < K; kt += 32) {
        loadTile(kt);       // global->VGPR for tile k+1 (latency hidden by MFMAs)
        compute();          // consume LDS tile k
        __syncthreads();    // all waves done reading LDS (lgkm only, no vm drain)
        writeTile();        // vmcnt wait lands here, after compute
        __syncthreads();
    }
    compute();

    // Epilogue. C/D layout (verified m89): col = lane&15, row = quad*4 + reg.
    #pragma unroll
    for (int j = 0; j < 4; ++j) {
        int col = col0 + wn * 64 + j * 16 + l15;
        float bcol = bias ? bias[col] : 0.0f;
        #pragma unroll
        for (int i = 0; i < 4; ++i) {
            #pragma unroll
            for (int t = 0; t < 4; ++t) {
                int r = row0 + wm * 64 + i * 16 + quad * 4 + t;
                float v = acc[i][j][t] * descale + bcol;
                if (relu) v = fmaxf(v, 0.0f);
                size_t o = (size_t)r * N + col;
                if (outF) outF[o] = v;
                if (outHi) {
                    float sv = v * outScale;
                    _Float16 h = (_Float16)sv;
                    outHi[o] = h;
                    outLo[o] = (_Float16)(sv - (float)h);
                }
            }
        }
    }
}

// ---------------------------------------------------------------------------
// Transpose fp32 [R][C] -> scaled f16 hi/lo [C][R]. 32x32 LDS tiles.
// ---------------------------------------------------------------------------
__global__ __launch_bounds__(256)
void transpose_split(const float* __restrict__ src, _Float16* __restrict__ hi,
                     _Float16* __restrict__ lo, float scale, int R, int C)
{
    __shared__ float t[32][33];
    int tx = threadIdx.x & 31, ty = threadIdx.x >> 5;
    int r0 = blockIdx.y * 32, c0 = blockIdx.x * 32;
    #pragma unroll
    for (int p = 0; p < 4; ++p) {
        int r = ty + p * 8;
        t[r][tx] = src[(size_t)(r0 + r) * C + c0 + tx];
    }
    __syncthreads();
    #pragma unroll
    for (int p = 0; p < 4; ++p) {
        int oc = ty + p * 8;
        float v = t[tx][oc] * scale;
        _Float16 h = (_Float16)v;
        size_t o = (size_t)(c0 + oc) * R + r0 + tx;
        hi[o] = h;
        lo[o] = (_Float16)(v - (float)h);
    }
}

// ---------------------------------------------------------------------------
// Normalize codebook rows (fp32 math), emit scaled f16 hi/lo [K][E].
// ---------------------------------------------------------------------------
__global__ __launch_bounds__(256)
void norm_codes(const float* __restrict__ emb, _Float16* __restrict__ cnHi,
                _Float16* __restrict__ cnLo)
{
    int wave = threadIdx.x >> 6;
    int lane = threadIdx.x & 63;
    int c = blockIdx.x * 4 + wave;
    if (c >= KCODE) return;
    const float* er = emb + (size_t)c * EMB;
    float ss = 0.0f;
    #pragma unroll
    for (int k = lane; k < EMB; k += 64) { float v = er[k]; ss += v * v; }
    #pragma unroll
    for (int off = 32; off > 0; off >>= 1) ss += __shfl_down(ss, off, 64);
    ss = __shfl(ss, 0, 64);
    float inv = 1.0f / (sqrtf(ss) + 1e-12f);
    #pragma unroll
    for (int k = lane; k < EMB; k += 64) {
        float v = er[k] * inv * SC_CODE;
        _Float16 h = (_Float16)v;
        cnHi[(size_t)c * EMB + k] = h;
        cnLo[(size_t)c * EMB + k] = (_Float16)(v - (float)h);
    }
}

// ---------------------------------------------------------------------------
// Per-row argmax over S[B,K] -> one-hot, vq_feat gather, index.
// First-index tie-break (numpy argmax semantics).
// ---------------------------------------------------------------------------
__global__ __launch_bounds__(256)
void argmax_vq(const float* __restrict__ S, const float* __restrict__ emb,
               float* __restrict__ onehot, float* __restrict__ vqfeat,
               int* __restrict__ idxOut)
{
    int wave = threadIdx.x >> 6;
    int lane = threadIdx.x & 63;
    int row = blockIdx.x * 4 + wave;
    if (row >= BATCH) return;

    const float* s = S + (size_t)row * KCODE;
    float bestV = -3.402823466e+38f;
    int   bestI = 0;
    #pragma unroll
    for (int c = lane; c < KCODE; c += 64) {
        float v = s[c];
        if (v > bestV) { bestV = v; bestI = c; }
    }
    #pragma unroll
    for (int off = 32; off > 0; off >>= 1) {
        float ov = __shfl_down(bestV, off, 64);
        int   oi = __shfl_down(bestI, off, 64);
        if (ov > bestV || (ov == bestV && oi < bestI)) { bestV = ov; bestI = oi; }
    }
    bestI = __shfl(bestI, 0, 64);
    if (lane == 0) idxOut[row] = bestI;

    float* oh = onehot + (size_t)row * KCODE;
    #pragma unroll
    for (int c = lane; c < KCODE; c += 64) oh[c] = (c == bestI) ? 1.0f : 0.0f;

    const float* er = emb + (size_t)bestI * EMB;
    float* vr = vqfeat + (size_t)row * EMB;
    #pragma unroll
    for (int c = lane; c < EMB; c += 64) vr[c] = er[c];
}

__global__ __launch_bounds__(256)
void gather_decoded(const float* __restrict__ Dcode, const int* __restrict__ idx,
                    float* __restrict__ out)
{
    int row = blockIdx.x;
    int k = idx[row];
    const float4* src = (const float4*)(Dcode + (size_t)k * FEAT);
    float4* dst = (float4*)(out + (size_t)row * FEAT);
    #pragma unroll
    for (int i = threadIdx.x; i < FEAT / 4; i += 256) dst[i] = src[i];
}

__global__ __launch_bounds__(256)
void copy_f4(const float* __restrict__ src, float* __restrict__ dst, int n4)
{
    int i = blockIdx.x * 256 + threadIdx.x;
    if (i < n4) ((float4*)dst)[i] = ((const float4*)src)[i];
}

// ---------------------------------------------------------------------------
extern "C" void kernel_launch(void* const* d_in, const int* in_sizes, int n_in,
                              void* d_out, int out_size, void* d_ws, size_t ws_size,
                              hipStream_t stream)
{
    const float* x      = (const float*)d_in[0];
    const float* enc_w1 = (const float*)d_in[1];
    const float* enc_b1 = (const float*)d_in[2];
    const float* enc_w2 = (const float*)d_in[3];
    const float* enc_b2 = (const float*)d_in[4];
    const float* emb    = (const float*)d_in[5];
    const float* dec_w1 = (const float*)d_in[6];
    const float* dec_b1 = (const float*)d_in[7];
    const float* dec_w2 = (const float*)d_in[8];
    const float* dec_b2 = (const float*)d_in[9];

    float* out = (float*)d_out;
    float* out_encoded = out;
    float* out_vqfeat  = out + (size_t)BATCH * EMB;
    float* out_onehot  = out + (size_t)2 * BATCH * EMB;
    float* out_decoded = out + (size_t)2 * BATCH * EMB + (size_t)BATCH * KCODE;
    float* out_emb     = out_decoded + (size_t)BATCH * FEAT;

    // ------- workspace layout -------
    char* w = (char*)d_ws;
    _Float16* w1T_hi = (_Float16*)w;  w += (size_t)FEAT * MID * 2;
    _Float16* w1T_lo = (_Float16*)w;  w += (size_t)FEAT * MID * 2;
    _Float16* w2T_hi = (_Float16*)w;  w += (size_t)MID * EMB * 2;
    _Float16* w2T_lo = (_Float16*)w;  w += (size_t)MID * EMB * 2;
    _Float16* h_hi   = (_Float16*)w;  w += (size_t)BATCH * MID * 2;
    _Float16* h_lo   = (_Float16*)w;  w += (size_t)BATCH * MID * 2;
    _Float16* enc_hi = (_Float16*)w;  w += (size_t)BATCH * EMB * 2;
    _Float16* enc_lo = (_Float16*)w;  w += (size_t)BATCH * EMB * 2;
    _Float16* cn_hi  = (_Float16*)w;  w += (size_t)KCODE * EMB * 2;
    _Float16* cn_lo  = (_Float16*)w;  w += (size_t)KCODE * EMB * 2;
    _Float16* wd1T_hi= (_Float16*)w;  w += (size_t)MID * EMB * 2;
    _Float16* wd1T_lo= (_Float16*)w;  w += (size_t)MID * EMB * 2;
    _Float16* wd2T_hi= (_Float16*)w;  w += (size_t)FEAT * MID * 2;
    _Float16* wd2T_lo= (_Float16*)w;  w += (size_t)FEAT * MID * 2;
    _Float16* tm_hi  = (_Float16*)w;  w += (size_t)KCODE * MID * 2;
    _Float16* tm_lo  = (_Float16*)w;  w += (size_t)KCODE * MID * 2;
    float*    S      = (float*)w;     w += (size_t)BATCH * KCODE * 4;
    float*    Dc     = (float*)w;     w += (size_t)KCODE * FEAT * 4;
    int*      idx    = (int*)w;

    // --- prep: weight transposes/splits, codebook norm, emb passthrough ---
    transpose_split<<<dim3(MID / 32, FEAT / 32), dim3(256), 0, stream>>>(
        enc_w1, w1T_hi, w1T_lo, SC_W, FEAT, MID);
    transpose_split<<<dim3(EMB / 32, MID / 32), dim3(256), 0, stream>>>(
        enc_w2, w2T_hi, w2T_lo, SC_W, MID, EMB);
    transpose_split<<<dim3(MID / 32, EMB / 32), dim3(256), 0, stream>>>(
        dec_w1, wd1T_hi, wd1T_lo, SC_W, EMB, MID);
    transpose_split<<<dim3(FEAT / 32, MID / 32), dim3(256), 0, stream>>>(
        dec_w2, wd2T_hi, wd2T_lo, SC_W, MID, FEAT);
    norm_codes<<<dim3(KCODE / 4), dim3(256), 0, stream>>>(emb, cn_hi, cn_lo);
    copy_f4<<<dim3((KCODE * EMB / 4 + 255) / 256), dim3(256), 0, stream>>>(
        emb, out_emb, KCODE * EMB / 4);

    // --- G1: h = relu(x @ w1 + b1), fp32 A split in-kernel, swizzled 1-D grid
    gemm_rp<<<dim3((BATCH / 128) * (MID / 128)), dim3(256), 0, stream>>>(
        x, nullptr, nullptr, w1T_hi, w1T_lo, enc_b1, SC_X, DS_G1, 1,
        nullptr, h_hi, h_lo, SC_H, BATCH, MID, FEAT, 3, 1);

    // --- G2: encoded = h @ w2 + b2 (fp32 out + split out)
    gemm_rp<<<dim3(EMB / 128, BATCH / 128), dim3(256), 0, stream>>>(
        nullptr, h_hi, h_lo, w2T_hi, w2T_lo, enc_b2, 0.0f, DS_G2, 0,
        out_encoded, enc_hi, enc_lo, SC_ENC, BATCH, EMB, MID, 3, 0);

    // --- G3: S = encoded @ cn^T (feature norm skipped: argmax-invariant)
    gemm_rp<<<dim3((BATCH / 128) * (KCODE / 128)), dim3(256), 0, stream>>>(
        nullptr, enc_hi, enc_lo, cn_hi, cn_lo, nullptr, 0.0f, DS_G3, 0,
        S, nullptr, nullptr, 1.0f, BATCH, KCODE, EMB, 3, 1);

    // --- argmax -> one-hot, vq_feat, idx
    argmax_vq<<<dim3(BATCH / 4), dim3(256), 0, stream>>>(
        S, emb, out_onehot, out_vqfeat, idx);

    // --- decoder on codebook only (512 distinct rows), f16 single-term MFMA
    gemm_rp<<<dim3(MID / 128, KCODE / 128), dim3(256), 0, stream>>>(
        emb, nullptr, nullptr, wd1T_hi, wd1T_lo, dec_b1, SC_EMB, DS_D1, 1,
        nullptr, tm_hi, tm_lo, SC_TM, KCODE, MID, EMB, 1, 0);
    gemm_rp<<<dim3(FEAT / 128, KCODE / 128), dim3(256), 0, stream>>>(
        nullptr, tm_hi, tm_lo, wd2T_hi, wd2T_lo, dec_b2, 0.0f, DS_D2, 1,
        Dc, nullptr, nullptr, 1.0f, KCODE, FEAT, MID, 1, 0);

    // --- decoded[i] = Dcode[idx[i]]
    gather_decoded<<<dim3(BATCH), dim3(256), 0, stream>>>(Dc, idx, out_decoded);
}